// Round 15
// baseline (393.320 us; speedup 1.0000x reference)
//
#include <hip/hip_runtime.h>

#define DT 0.001f
#define GAMMA 2.0f

#define KSTEPS 120        // steps per launch -> 9 launches (8x120 + 40; 40%8==0)
#define HALOBP 120        // block halo in PAIRS = KSTEPS (radius 1 pair/step)
#define TILEP  144        // interior pairs per block -> 114 blocks
#define REGP   384        // region pairs = NW*WINT
#define NW     8          // waves per block (512 thr -> 2 waves/SIMD)
#define WINT   48         // interior lanes per wave (1 pair each)
#define WHALO  8          // wave halo lanes per side = JEXCH
#define JEXCH  8          // steps between intra-block LDS exchanges
#define SBATCH 4          // trajectory store batch (regs)
#define NTHREADS 512

typedef float v2f __attribute__((ext_vector_type(2)));

// LDS-only barrier (global trajectory stores stay in flight).
__device__ __forceinline__ void lds_barrier() {
    asm volatile("s_waitcnt lgkmcnt(0)" ::: "memory");
    __builtin_amdgcn_s_barrier();
    asm volatile("" ::: "memory");
}

// DPP wave-wide shifts (bound_ctrl: OOB lanes get 0 -> lands only in trapezoid halo)
__device__ __forceinline__ float dpp_shl1(float x) {   // lane i <- lane i+1
    return __int_as_float(__builtin_amdgcn_update_dpp(
        0, __float_as_int(x), 0x130, 0xF, 0xF, true));
}
__device__ __forceinline__ float dpp_shr1(float x) {   // lane i <- lane i-1
    return __int_as_float(__builtin_amdgcn_update_dpp(
        0, __float_as_int(x), 0x138, 0xF, 0xF, true));
}

// Two nodes (one pair) per lane, 8 waves/block (2 waves/SIMD preserved —
// R6's failure was dropping to 1 wave/SIMD). Radius = 1 lane/step: wave halo 8
// covers JEXCH=8, block halo 120 pairs covers KSTEPS=120 -> 9 launches.
// Per-node arithmetic expressions identical to the 286us version
// (interior bit-identical; absmax must stay exactly 32.0).
__global__ __launch_bounds__(NTHREADS) void chunk_kernel(
    const float4* __restrict__ xin, const float4* __restrict__ vin,
    float4* __restrict__ xout, float4* __restrict__ vout,
    const int*   __restrict__ buckle,      // (H,4) int32
    const float* __restrict__ thetas_ss,   // (H,)
    const float* __restrict__ rest_len,    // (H+1,)
    const float* __restrict__ kstiff_p,
    const float* __restrict__ ksoft_p,
    const float* __restrict__ kstretch_p,
    const float* __restrict__ init_pos,
    float* __restrict__ out,
    int N, int H, int n_coords, int t0, int ksteps, int n_steps)
{
    __shared__ float4 xch[2][REGP];        // pair positions (double-buffered)
    __shared__ float4 vch[2][REGP];        // pair velocities

    const int lane = threadIdx.x & 63;
    const int w    = threadIdx.x >> 6;
    const int rp   = w * WINT + lane - WHALO;           // region pair (may be OOB)
    const int tsp  = blockIdx.x * TILEP;                // tile start (pairs)
    const int jpa  = tsp - HALOBP + rp;                 // global pair index
    const int jga  = 2 * jpa;                           // node a (even)
    const int jgb  = jga + 1;                           // node b
    const int NP   = N >> 1;                            // 16385 pairs (N=32770)
    const bool rvalid = (rp >= 0) && (rp < REGP);
    const int  jcp  = min(max(jpa, 0), NP - 1);         // clamped pair load index

    const float kS  = kstiff_p[0];
    const float kw  = ksoft_p[0];
    const float kst = kstretch_p[0];

    // per-entity validity masks folded into hoisted constants (NaN-safe)
    const bool eokA = (jga >= 0) && (jga <= N - 2);
    const bool eokB = (jgb >= 0) && (jgb <= N - 2);
    const bool hokA = (jga >= 0) && (jga < H);
    const bool hokB = (jgb >= 0) && (jgb < H);

    const float rlA    = rest_len[min(max(jga, 0), H)];
    const float rlB    = rest_len[min(max(jgb, 0), H)];
    const float emaskA = eokA ? 1.0f : 0.0f,  emaskB = eokB ? 1.0f : 0.0f;
    const float efixA  = eokA ? 0.0f : 1.0f,  efixB  = eokB ? 0.0f : 1.0f;
    const float kstA   = eokA ? kst : 0.0f,   kstB   = eokB ? kst : 0.0f;
    const float kstrlA = kst * rlA,           kstrlB = kst * rlB;
    const float hfixA  = hokA ? 0.0f : 1.0f,  hfixB  = hokB ? 0.0f : 1.0f;

    float tssA = 0.f, npfA = 0.f, tssB = 0.f, npfB = 0.f;
    if (hokA) {
        tssA = thetas_ss[jga];
        int4 bk = reinterpret_cast<const int4*>(buckle)[jga];
        npfA = (float)((bk.x == 1) + (bk.y == 1) + (bk.z == 1) + (bk.w == 1));
    }
    if (hokB) {
        tssB = thetas_ss[jgb];
        int4 bk = reinterpret_cast<const int4*>(buckle)[jgb];
        npfB = (float)((bk.x == 1) + (bk.y == 1) + (bk.z == 1) + (bk.w == 1));
    }
    const float ntssA = -tssA, ntssB = -tssB;
    const float npf4A = 4.0f - npfA, npf4B = 4.0f - npfB;
    const float dKlA  = hokA ? (kS - kw) : 0.0f, dKlB  = hokB ? (kS - kw) : 0.0f;
    const float kw4A  = hokA ? 4.0f * kw : 0.0f, kw4B  = hokB ? 4.0f * kw : 0.0f;

    const bool pinned = (jpa == 0);                     // pair 0 = nodes 0,1
    float4 pin4 = make_float4(0.f, 0.f, 0.f, 0.f);
    if (pinned) pin4 = reinterpret_cast<const float4*>(init_pos)[0];

    const bool wave_int = (lane >= WHALO) && (lane < WHALO + WINT);
    const bool writer   = wave_int && (rp >= HALOBP) && (rp < HALOBP + TILEP)
                          && (jpa >= 0) && (jpa < NP);

    v2f pa, pb, va, vb;
    if (t0 == 0) {
        float4 P0 = reinterpret_cast<const float4*>(init_pos)[jcp];
        pa.x = P0.x; pa.y = P0.y; pb.x = P0.z; pb.y = P0.w;
        va.x = va.y = vb.x = vb.y = 0.0f;
    } else {
        float4 P0 = xin[jcp];
        float4 V0 = vin[jcp];
        pa.x = P0.x; pa.y = P0.y; pb.x = P0.z; pb.y = P0.w;
        va.x = V0.x; va.y = V0.y; vb.x = V0.z; vb.y = V0.w;
    }

    float4* tptr = reinterpret_cast<float4*>(out + (size_t)(t0 + 1) * (size_t)n_coords) + jcp;
    const size_t ts4 = (size_t)(n_coords / 4);   // float4 elements per row

    const float C998 = 1.0f - GAMMA * DT;

    for (int s0 = 0; s0 < ksteps; s0 += SBATCH) {
        if (s0 > 0 && (s0 & (JEXCH - 1)) == 0) {        // exchange every 8 steps
            int buf = (s0 >> 3) & 1;
            if (wave_int && rvalid) {
                xch[buf][rp] = make_float4(pa.x, pa.y, pb.x, pb.y);
                vch[buf][rp] = make_float4(va.x, va.y, vb.x, vb.y);
            }
            lds_barrier();
            if (rvalid) {
                float4 f4 = xch[buf][rp];
                pa.x = f4.x; pa.y = f4.y; pb.x = f4.z; pb.y = f4.w;
                float4 g4 = vch[buf][rp];
                va.x = g4.x; va.y = g4.y; vb.x = g4.z; vb.y = g4.w;
            }
        }
        float4 sbuf[SBATCH];               // 4-step trajectory batch (regs)
        #pragma unroll
        for (int u = 0; u < SBATCH; ++u) {
            // next lane's a-position; edges a (a->b), b (b->next a), c = shl(ea)
            v2f na; na.x = dpp_shl1(pa.x); na.y = dpp_shl1(pa.y);
            v2f ea = pb - pa;
            v2f eb = na - pb;
            v2f ec; ec.x = dpp_shl1(ea.x); ec.y = dpp_shl1(ea.y);

            float l2a  = fmaf(ea.x, ea.x, fmaf(ea.y, ea.y, efixA));
            float irta = __builtin_amdgcn_rsqf(l2a) * emaskA;
            float il2a = irta * irta;
            float sea  = fmaf(-kstrlA, irta, kstA);

            float l2b  = fmaf(eb.x, eb.x, fmaf(eb.y, eb.y, efixB));
            float irtb = __builtin_amdgcn_rsqf(l2b) * emaskB;
            float il2b = irtb * irtb;
            float seb  = fmaf(-kstrlB, irtb, kstB);

            // hinge a: edges (ea, eb)
            float cra = ea.x * eb.y - ea.y * eb.x;
            float dda = fmaf(ea.x, eb.x, fmaf(ea.y, eb.y, hfixA));
            float ta  = cra * __builtin_amdgcn_rcpf(dda);
            float t2a = ta * ta;
            float pA = fmaf(t2a, 0.11111111f, -0.14285715f);
            pA = fmaf(t2a, pA, 0.2f);
            pA = fmaf(t2a, pA, -0.33333334f);
            pA = fmaf(t2a, pA, 1.0f);
            float thA = pA * ta;
            float nsA = (thA > ntssA ? npfA : 0.0f) + (thA < tssA ? npf4A : 0.0f);
            float KA  = fmaf(nsA, dKlA, kw4A);
            float ga  = KA * (thA - tssA);

            // hinge b: edges (eb, ec)
            float crb = eb.x * ec.y - eb.y * ec.x;
            float ddb = fmaf(eb.x, ec.x, fmaf(eb.y, ec.y, hfixB));
            float tb  = crb * __builtin_amdgcn_rcpf(ddb);
            float t2b = tb * tb;
            float pB = fmaf(t2b, 0.11111111f, -0.14285715f);
            pB = fmaf(t2b, pB, 0.2f);
            pB = fmaf(t2b, pB, -0.33333334f);
            pB = fmaf(t2b, pB, 1.0f);
            float thB = pB * tb;
            float nsB = (thB > ntssB ? npfB : 0.0f) + (thB < tssB ? npf4B : 0.0f);
            float KB  = fmaf(nsB, dKlB, kw4B);
            float gb  = KB * (thB - tssB);

            // edge forces: coef_e = (g_{e-1} - g_e)/len^2
            float gprev = dpp_shr1(gb);                  // g_{jga-1} = prev lane's gb
            float coefa = (gprev - ga) * il2a;
            float coefb = (ga - gb) * il2b;
            v2f Fa, Fb;
            Fa.x = fmaf(coefa, -ea.y, sea * ea.x);
            Fa.y = fmaf(coefa,  ea.x, sea * ea.y);
            Fb.x = fmaf(coefb, -eb.y, seb * eb.x);
            Fb.y = fmaf(coefb,  eb.x, seb * eb.y);
            v2f Fp; Fp.x = dpp_shr1(Fb.x); Fp.y = dpp_shr1(Fb.y);

            v2f fa = Fa - Fp;                            // node a
            v2f fb = Fb - Fa;                            // node b
            va = va * C998 + fa * DT;
            pa = pa + va * DT;
            vb = vb * C998 + fb * DT;
            pb = pb + vb * DT;
            if (tsp == 0) {                              // uniform guard
                if (pinned) {
                    va.x = va.y = vb.x = vb.y = 0.0f;
                    pa.x = pin4.x; pa.y = pin4.y; pb.x = pin4.z; pb.y = pin4.w;
                }
            }
            sbuf[u] = make_float4(pa.x, pa.y, pb.x, pb.y);
        }
        if (writer) {
            #pragma unroll
            for (int u = 0; u < SBATCH; ++u) {
                tptr[(size_t)u * ts4] = sbuf[u];
            }
        }
        tptr += (size_t)SBATCH * ts4;
    }

    if (writer) {
        xout[jpa] = make_float4(pa.x, pa.y, pb.x, pb.y);
        vout[jpa] = make_float4(va.x, va.y, vb.x, vb.y);
        if (t0 + ksteps == n_steps) {
            reinterpret_cast<float4*>(out)[jpa] = make_float4(pa.x, pa.y, pb.x, pb.y);
        }
    }
}

extern "C" void kernel_launch(void* const* d_in, const int* in_sizes, int n_in,
                              void* d_out, int out_size, void* d_ws, size_t ws_size,
                              hipStream_t stream) {
    const float* init_pos  = (const float*)d_in[0];
    const int*   buckle    = (const int*)d_in[1];
    const float* thetas_ss = (const float*)d_in[2];
    const float* rest_len  = (const float*)d_in[3];
    const float* kstiff    = (const float*)d_in[4];
    const float* ksoft     = (const float*)d_in[5];
    const float* kstretch  = (const float*)d_in[6];

    const int n_coords = in_sizes[0];             // 65540
    const int N = n_coords / 2;                   // 32770 nodes
    const int H = in_sizes[2];                    // 32768 hinges
    const int n_steps = out_size / n_coords - 1;  // 1000
    const int NP = N / 2;                         // 16385 pairs

    float* out = (float*)d_out;
    float4* stAx = (float4*)d_ws;                 // NP float4 pair positions (A)
    float4* stAv = stAx + NP;
    float4* stBx = stAv + NP;
    float4* stBv = stBx + NP;

    const int nblocks = (NP + TILEP - 1) / TILEP; // 114
    float4* xin = stAx; float4* vin = stAv;
    float4* xout = stBx; float4* vout = stBv;
    for (int t0 = 0; t0 < n_steps; t0 += KSTEPS) {
        int k = n_steps - t0; if (k > KSTEPS) k = KSTEPS;
        chunk_kernel<<<nblocks, NTHREADS, 0, stream>>>(
            xin, vin, xout, vout,
            buckle, thetas_ss, rest_len, kstiff, ksoft, kstretch,
            init_pos, out, N, H, n_coords, t0, k, n_steps);
        float4* t1 = xin; xin = xout; xout = t1;
        float4* t2 = vin; vin = vout; vout = t2;
    }
}

// Round 16
// 287.748 us; speedup vs baseline: 1.3669x; 1.3669x over previous
//
#include <hip/hip_runtime.h>

#define DT 0.001f
#define GAMMA 2.0f

#define KSTEPS 60         // steps per launch (last chunk: 40; both %4==0)
#define HALOB  120        // block halo = 2*KSTEPS (radius 2 nodes/step)
#define TILE   144        // interior nodes per block -> 228 blocks (<= 256 CUs; 257+ would straggle)
#define REGION 384        // TILE + 2*HALOB = NW*WINT
#define NW     8          // waves per block (512 thr -> 2 waves/SIMD: proven optimum)
#define WINT   48         // wave-interior lanes (1 node each)
#define WHALO  8          // wave halo lanes per side = 2*JEXCH
#define JEXCH  4          // steps between intra-block LDS exchanges
#define NTHREADS 512

typedef float v2f __attribute__((ext_vector_type(2)));

// LDS-only barrier (global trajectory stores stay in flight).
__device__ __forceinline__ void lds_barrier() {
    asm volatile("s_waitcnt lgkmcnt(0)" ::: "memory");
    __builtin_amdgcn_s_barrier();
    asm volatile("" ::: "memory");
}

// DPP wave-wide shifts (bound_ctrl: OOB lanes get 0 -> lands only in trapezoid halo)
__device__ __forceinline__ float dpp_shl1(float x) {   // lane i <- lane i+1
    return __int_as_float(__builtin_amdgcn_update_dpp(
        0, __float_as_int(x), 0x130, 0xF, 0xF, true));
}
__device__ __forceinline__ float dpp_shr1(float x) {   // lane i <- lane i-1
    return __int_as_float(__builtin_amdgcn_update_dpp(
        0, __float_as_int(x), 0x138, 0xF, 0xF, true));
}

// Chunk kernel (17 launches, R14 skeleton). Hinge angle via asin form:
// theta = asin(cr * irt_j * irt_{j+1}) — reuses the stretch term's 1/len,
// gets the neighbor's via 1 DPP, eliminates dd + v_rcp (2nd trans op) + hfix.
// asin series through s^9: trunc err <= 3e-8 on |s|<=0.296.
__global__ __launch_bounds__(NTHREADS) void chunk_kernel(
    const float* __restrict__ xin, const float* __restrict__ vin,
    float* __restrict__ xout, float* __restrict__ vout,
    const int*   __restrict__ buckle,      // (H,4) int32
    const float* __restrict__ thetas_ss,   // (H,)
    const float* __restrict__ rest_len,    // (H+1,)
    const float* __restrict__ kstiff_p,
    const float* __restrict__ ksoft_p,
    const float* __restrict__ kstretch_p,
    const float* __restrict__ init_pos,
    float* __restrict__ out,
    int N, int H, int n_coords, int t0, int ksteps, int n_steps)
{
    __shared__ float4 xch[2][REGION];      // double-buffered pos+vel exchange

    const int lane = threadIdx.x & 63;
    const int w    = threadIdx.x >> 6;
    const int r    = w * WINT + lane - WHALO;           // region node (may be OOB)
    const int tile_start = blockIdx.x * TILE;
    const int jg   = tile_start - HALOB + r;            // global node
    const bool rvalid = (r >= 0) && (r < REGION);
    const bool nvalid = (jg >= 0) && (jg < N);
    const int  jc   = min(max(jg, 0), N - 1);           // clamped load index

    const float kS  = kstiff_p[0];
    const float kw  = ksoft_p[0];
    const float kst = kstretch_p[0];

    const bool edge_ok  = (jg >= 0) && (jg <= N - 2);
    const bool hinge_ok = (jg >= 0) && (jg < H);

    // hoisted per-lane constants with validity folded in (NaN-safe)
    const float rl     = rest_len[min(max(jg, 0), H)];
    const float emask  = edge_ok ? 1.0f : 0.0f;
    const float efix   = edge_ok ? 0.0f : 1.0f;   // l2 guard: keeps rsq finite
    const float kst_l  = edge_ok ? kst : 0.0f;
    const float kstrl  = kst * rl;
    float tss = 0.0f, npf = 0.0f;
    if (hinge_ok) {
        tss = thetas_ss[jg];
        int4 bk = reinterpret_cast<const int4*>(buckle)[jg];
        npf = (float)((bk.x == 1) + (bk.y == 1) + (bk.z == 1) + (bk.w == 1));
    }
    const float ntss  = -tss;
    const float npf4m = 4.0f - npf;
    const float dKl   = hinge_ok ? (kS - kw) : 0.0f;   // K = fma(ns,dKl,kw4l)
    const float kw4l  = hinge_ok ? 4.0f * kw : 0.0f;

    const bool pinned = nvalid && (jg < 2);
    v2f pin = {0.0f, 0.0f};
    if (pinned) { pin.x = init_pos[2 * jg]; pin.y = init_pos[2 * jg + 1]; }

    const bool wave_int = (lane >= WHALO) && (lane < WHALO + WINT);
    const bool writer   = wave_int && (r >= HALOB) && (r < HALOB + TILE) && nvalid;

    v2f p, v;
    if (t0 == 0) {
        float2 P0 = reinterpret_cast<const float2*>(init_pos)[jc];
        p.x = P0.x; p.y = P0.y;
        v.x = 0.0f; v.y = 0.0f;
    } else {
        float2 P0 = reinterpret_cast<const float2*>(xin)[jc];
        float2 V0 = reinterpret_cast<const float2*>(vin)[jc];
        p.x = P0.x; p.y = P0.y;
        v.x = V0.x; v.y = V0.y;
    }

    float2* tptr = reinterpret_cast<float2*>(out + (size_t)(t0 + 1) * (size_t)n_coords) + jc;
    const size_t tstride = (size_t)(n_coords / 2);   // float2 elements per row

    const float C998 = 1.0f - GAMMA * DT;

    for (int s0 = 0; s0 < ksteps; s0 += JEXCH) {
        if (s0 > 0) {
            int buf = (s0 >> 2) & 1;
            if (wave_int && rvalid) xch[buf][r] = make_float4(p.x, p.y, v.x, v.y);
            lds_barrier();
            if (rvalid) {
                float4 f4 = xch[buf][r];
                p.x = f4.x; p.y = f4.y; v.x = f4.z; v.y = f4.w;
            }
        }
        float2 sbuf[JEXCH];                // group-local trajectory buffer (regs)
        #pragma unroll
        for (int u = 0; u < JEXCH; ++u) {
            v2f q;  q.x  = dpp_shl1(p.x); q.y  = dpp_shl1(p.y);
            v2f e  = q - p;
            v2f en; en.x = dpp_shl1(e.x); en.y = dpp_shl1(e.y);

            float l2   = fmaf(e.x, e.x, fmaf(e.y, e.y, efix));
            float irt  = __builtin_amdgcn_rsqf(l2) * emask;  // masked 1/len
            float il2  = irt * irt;
            float se   = fmaf(-kstrl, irt, kst_l);           // kst*(len-rl)/len

            // hinge: theta = asin(cr * irt_j * irt_{j+1}); |s|<=1 always
            // (Cauchy-Schwarz), so no rcp/NaN path even on halo garbage.
            float cr   = e.x * en.y - e.y * en.x;
            float irtn = dpp_shl1(irt);                      // next edge's 1/len
            float s    = cr * (irt * irtn);
            float s2   = s * s;
            float pp = fmaf(s2, 0.030381944f, 0.044642857f); // 105/3456, 15/336
            pp = fmaf(s2, pp, 0.075f);                       // 3/40
            pp = fmaf(s2, pp, 0.16666667f);                  // 1/6
            pp = fmaf(s2, pp, 1.0f);
            float th   = pp * s;
            float thmt = th - tss;
            float ns = (th > ntss ? npf : 0.0f) + (th < tss ? npf4m : 0.0f);
            float K  = fmaf(ns, dKl, kw4l);
            float g  = K * thmt;

            float gm   = dpp_shr1(g);
            float coef = (gm - g) * il2;
            v2f F;
            F.x = fmaf(coef, -e.y, se * e.x);
            F.y = fmaf(coef,  e.x, se * e.y);
            v2f Fp; Fp.x = dpp_shr1(F.x); Fp.y = dpp_shr1(F.y);

            v2f f = F - Fp;
            v = v * C998 + f * DT;
            p = p + v * DT;
            if (tile_start == 0) {                            // uniform guard
                if (pinned) { v.x = 0.0f; v.y = 0.0f; p = pin; }
            }
            sbuf[u] = make_float2(p.x, p.y);
        }
        if (writer) {
            #pragma unroll
            for (int u = 0; u < JEXCH; ++u) {
                tptr[(size_t)u * tstride] = sbuf[u];
            }
        }
        tptr += (size_t)JEXCH * tstride;
    }

    if (writer) {
        reinterpret_cast<float2*>(xout)[jg] = make_float2(p.x, p.y);
        reinterpret_cast<float2*>(vout)[jg] = make_float2(v.x, v.y);
        if (t0 + ksteps == n_steps) {
            reinterpret_cast<float2*>(out)[jg] = make_float2(p.x, p.y);  // x_final
        }
    }
}

extern "C" void kernel_launch(void* const* d_in, const int* in_sizes, int n_in,
                              void* d_out, int out_size, void* d_ws, size_t ws_size,
                              hipStream_t stream) {
    const float* init_pos  = (const float*)d_in[0];
    const int*   buckle    = (const int*)d_in[1];
    const float* thetas_ss = (const float*)d_in[2];
    const float* rest_len  = (const float*)d_in[3];
    const float* kstiff    = (const float*)d_in[4];
    const float* ksoft     = (const float*)d_in[5];
    const float* kstretch  = (const float*)d_in[6];

    const int n_coords = in_sizes[0];             // 65540
    const int N = n_coords / 2;                   // 32770 nodes
    const int H = in_sizes[2];                    // 32768 hinges
    const int n_steps = out_size / n_coords - 1;  // 1000

    float* out = (float*)d_out;
    float* wsf = (float*)d_ws;
    float* sAx = wsf;
    float* sAv = wsf + n_coords;
    float* sBx = wsf + 2 * n_coords;
    float* sBv = wsf + 3 * n_coords;

    const int nblocks = (N + TILE - 1) / TILE;    // 228
    float* xin = sAx; float* vin = sAv;
    float* xout = sBx; float* vout = sBv;
    for (int t0 = 0; t0 < n_steps; t0 += KSTEPS) {
        int k = n_steps - t0; if (k > KSTEPS) k = KSTEPS;
        chunk_kernel<<<nblocks, NTHREADS, 0, stream>>>(
            xin, vin, xout, vout,
            buckle, thetas_ss, rest_len, kstiff, ksoft, kstretch,
            init_pos, out, N, H, n_coords, t0, k, n_steps);
        float* t1 = xin; xin = xout; xout = t1;
        float* t2 = vin; vin = vout; vout = t2;
    }
}